// Round 5
// baseline (281.645 us; speedup 1.0000x reference)
//
#include <hip/hip_runtime.h>

#define T   512
#define B   512
#define NT  64
#define NB  32              // batches per compute block
#define NWG (B / NB)        // 16 compute workgroups

typedef _Float16 h2   __attribute__((ext_vector_type(2)));
typedef _Float16 h8   __attribute__((ext_vector_type(8)));
typedef float    f16v __attribute__((ext_vector_type(16)));

__device__ __forceinline__ int cvtpk(float a, float b) {
    return __builtin_bit_cast(int, __builtin_amdgcn_cvt_pkrtz(a, b));
}
__device__ __forceinline__ h2  bch2(int u) { return __builtin_bit_cast(h2, u); }
__device__ __forceinline__ int bci(h2 u)   { return __builtin_bit_cast(int, u); }

// v_permlane32_swap_b32 x, y:
//   x' = { i<32: y[i+32],  i>=32: x[i] }
//   y' = { i<32: y[i],     i>=32: x[i-32] }
__device__ __forceinline__ void plswap(int& x, int& y) {
    asm volatile("v_permlane32_swap_b32 %0, %1" : "+v"(x), "+v"(y));
}

// ---------------------------------------------------------------------------
// Lockstep-batched CRF forward on the matrix pipe.
//
// State per compute wave: Q [NT=64 rows x NB=32 batch-cols] as f16 B-fragments
// of mfma_f32_32x32x16_f16 (layout verified on HW in round 4):
//   B-frag:  lane(n=l&31, hi=l>>5), Qw[ks][r] = (Q[k][n], Q[k+1][n]),
//            k = 16ks + 8hi + 2r
//   A-frag:  A[mt][ks].p[r] = (E[k][j], E[k+1][j]), j = 32mt + n  (E=exp(trans))
//   C/D:     lane(n,hi), reg 4g+u -> row 32mt + 8g + 4hi + u, col n
// Step: c = E^T Q (8 MFMA, 2 chains of 4, throughput-issued); per-column
// prompt power-of-2 renorm (k = exponent of row0 via one permlane bcast,
// applied as integer exponent subtract -- safe: E in [1,e) bounds the spread
// of p to e^+-1.45 around row0, so p*2^-(k+2) stays in [2^-10, 2^0]);
// X-scale in packed f16 (v_pk_mul); C/D -> B exchange via permlane32_swap:
//   for s in 0,1:  (a1,a0) = swap(Wl[2s+1], Wl[2s]);  Qw[2mt+s][2]=a1,
//   Qw[2mt+s][0]=a0  (and Wh -> slots 3,1)  -- no cndmask needed, the
//   register/lane algebra lines up exactly (derived from the verified layouts).
// Producer waves 1,2 stage X = exp(emissions) into a 16-step LDS ring
// (4 quarters, lead 2), wave 1 also stages the mask bits.
// ---------------------------------------------------------------------------
__global__ __launch_bounds__(192) void crf_mfma(
    const float* __restrict__ emissions,  // [T, B, NT]
    const int*   __restrict__ tags,       // [T, B]
    const int*   __restrict__ mask,       // [T, B]
    const float* __restrict__ startT,     // [NT]
    const float* __restrict__ endT,       // [NT]
    const float* __restrict__ trans,      // [NT, NT]
    float* __restrict__ out)
{
    const int wid = threadIdx.x >> 6;
    const int l   = threadIdx.x & 63;

    __shared__ __align__(16) int xw[16][2][2][NB][8];  // X f16-pair words, 64 KB
    __shared__ int mls[4][4][NB];                      // mask ring, 2 KB

    if (blockIdx.x < NWG) {
        const int b0 = blockIdx.x * NB;

        if (wid == 0) {
            // ================= compute wave =================
            const int n  = l & 31;
            const int hi = l >> 5;
            const int b  = b0 + n;

            union AU { h2 p[4]; h8 v; };
            AU A[2][4];
#pragma unroll
            for (int mt = 0; mt < 2; ++mt)
#pragma unroll
                for (int ks = 0; ks < 4; ++ks)
#pragma unroll
                    for (int r = 0; r < 4; ++r) {
                        const int k = 16*ks + 8*hi + 2*r;
                        const int j = 32*mt + n;
                        h2 e;
                        e.x = (_Float16)__expf(trans[k*NT + j]);
                        e.y = (_Float16)__expf(trans[(k+1)*NT + j]);
                        A[mt][ks].p[r] = e;
                    }

            // init state q0 = exp(startT + em0 - S0), S0 = row-0 shift
            const float S0 = startT[0] + emissions[(size_t)b * NT];
            int Qw[4][4];
#pragma unroll
            for (int ks = 0; ks < 4; ++ks)
#pragma unroll
                for (int r = 0; r < 4; ++r) {
                    const int k = 16*ks + 8*hi + 2*r;
                    const float v0 = __expf(startT[k]   + emissions[(size_t)b*NT + k]   - S0);
                    const float v1 = __expf(startT[k+1] + emissions[(size_t)b*NT + k+1] - S0);
                    Qw[ks][r] = cvtpk(v0, v1);
                }
            int K = 0;
            const f16v zc = {};

            __syncthreads();

#pragma unroll 1
            for (int q = 0; q < T/4; ++q) {
                int mreg[4];
#pragma unroll
                for (int tt = 0; tt < 4; ++tt) mreg[tt] = mls[q & 3][tt][n];

#pragma unroll
                for (int tt = 0; tt < 4; ++tt) {
                    const int t = 4*q + tt;
                    if (t == 0) continue;
                    const int slot = t & 15;

                    const int4 xA0 = *(const int4*)&xw[slot][0][hi][n][0];
                    const int4 xA1 = *(const int4*)&xw[slot][0][hi][n][4];
                    const int4 xB0 = *(const int4*)&xw[slot][1][hi][n][0];
                    const int4 xB1 = *(const int4*)&xw[slot][1][hi][n][4];

                    union QU { int w[4]; h8 v; };
                    QU q0{{Qw[0][0], Qw[0][1], Qw[0][2], Qw[0][3]}};
                    QU q1{{Qw[1][0], Qw[1][1], Qw[1][2], Qw[1][3]}};
                    QU q2{{Qw[2][0], Qw[2][1], Qw[2][2], Qw[2][3]}};
                    QU q3{{Qw[3][0], Qw[3][1], Qw[3][2], Qw[3][3]}};

                    f16v c0 = __builtin_amdgcn_mfma_f32_32x32x16_f16(A[0][0].v, q0.v, zc, 0,0,0);
                    f16v c1 = __builtin_amdgcn_mfma_f32_32x32x16_f16(A[1][0].v, q0.v, zc, 0,0,0);
                    c0 = __builtin_amdgcn_mfma_f32_32x32x16_f16(A[0][1].v, q1.v, c0, 0,0,0);
                    c1 = __builtin_amdgcn_mfma_f32_32x32x16_f16(A[1][1].v, q1.v, c1, 0,0,0);
                    c0 = __builtin_amdgcn_mfma_f32_32x32x16_f16(A[0][2].v, q2.v, c0, 0,0,0);
                    c1 = __builtin_amdgcn_mfma_f32_32x32x16_f16(A[1][2].v, q2.v, c1, 0,0,0);
                    c0 = __builtin_amdgcn_mfma_f32_32x32x16_f16(A[0][3].v, q3.v, c0, 0,0,0);
                    c1 = __builtin_amdgcn_mfma_f32_32x32x16_f16(A[1][3].v, q3.v, c1, 0,0,0);

                    // per-column exponent of row 0 (broadcast both halves)
                    int ra = __float_as_int(c0[0]), rb = ra;
                    plswap(ra, rb);                    // rb = row0 bits, all lanes
                    const int k  = ((rb >> 23) & 255) - 127;
                    const int sb = (k + 2) << 23;      // scale 2^-(k+2), exact

                    const int xm0[8] = {xA0.x,xA0.y,xA0.z,xA0.w, xA1.x,xA1.y,xA1.z,xA1.w};
                    const int xm1[8] = {xB0.x,xB0.y,xB0.z,xB0.w, xB1.x,xB1.y,xB1.z,xB1.w};

                    int Nw[4][4];
                    {   // tile mt = 0
                        int Wl[4], Wh[4];
#pragma unroll
                        for (int g = 0; g < 4; ++g) {
                            const float p0 = __int_as_float(__float_as_int(c0[4*g+0]) - sb);
                            const float p1 = __int_as_float(__float_as_int(c0[4*g+1]) - sb);
                            const float p2 = __int_as_float(__float_as_int(c0[4*g+2]) - sb);
                            const float p3 = __int_as_float(__float_as_int(c0[4*g+3]) - sb);
                            Wl[g] = bci(bch2(cvtpk(p0, p1)) * bch2(xm0[2*g]));
                            Wh[g] = bci(bch2(cvtpk(p2, p3)) * bch2(xm0[2*g+1]));
                        }
#pragma unroll
                        for (int s = 0; s < 2; ++s) {
                            int a1 = Wl[2*s+1], a0 = Wl[2*s];
                            plswap(a1, a0);
                            Nw[s][2] = a1; Nw[s][0] = a0;
                            int d1 = Wh[2*s+1], d0 = Wh[2*s];
                            plswap(d1, d0);
                            Nw[s][3] = d1; Nw[s][1] = d0;
                        }
                    }
                    {   // tile mt = 1
                        int Wl[4], Wh[4];
#pragma unroll
                        for (int g = 0; g < 4; ++g) {
                            const float p0 = __int_as_float(__float_as_int(c1[4*g+0]) - sb);
                            const float p1 = __int_as_float(__float_as_int(c1[4*g+1]) - sb);
                            const float p2 = __int_as_float(__float_as_int(c1[4*g+2]) - sb);
                            const float p3 = __int_as_float(__float_as_int(c1[4*g+3]) - sb);
                            Wl[g] = bci(bch2(cvtpk(p0, p1)) * bch2(xm1[2*g]));
                            Wh[g] = bci(bch2(cvtpk(p2, p3)) * bch2(xm1[2*g+1]));
                        }
#pragma unroll
                        for (int s = 0; s < 2; ++s) {
                            int a1 = Wl[2*s+1], a0 = Wl[2*s];
                            plswap(a1, a0);
                            Nw[2+s][2] = a1; Nw[2+s][0] = a0;
                            int d1 = Wh[2*s+1], d0 = Wh[2*s];
                            plswap(d1, d0);
                            Nw[2+s][3] = d1; Nw[2+s][1] = d0;
                        }
                    }

                    const bool mc = mreg[tt] != 0;
                    if (__ballot(mc) == ~0ull) {
                        K += k + 2;
#pragma unroll
                        for (int ks = 0; ks < 4; ++ks)
#pragma unroll
                            for (int r = 0; r < 4; ++r) Qw[ks][r] = Nw[ks][r];
                    } else {
                        K += mc ? (k + 2) : 0;
#pragma unroll
                        for (int ks = 0; ks < 4; ++ks)
#pragma unroll
                            for (int r = 0; r < 4; ++r)
                                Qw[ks][r] = mc ? Nw[ks][r] : Qw[ks][r];
                    }
                }
                __syncthreads();
            }

            // ---- finish: v_n = sum_j qhat[j][n] * exp(endT[j]) ----
            float v = 0.f;
#pragma unroll
            for (int ks = 0; ks < 4; ++ks)
#pragma unroll
                for (int r = 0; r < 4; ++r) {
                    const int k = 16*ks + 8*hi + 2*r;
                    const h2 qq = bch2(Qw[ks][r]);
                    v += (float)qq.x * __expf(endT[k]);
                    v += (float)qq.y * __expf(endT[k+1]);
                }
            v += __shfl_xor(v, 32);
            const float den = S0 + (float)K * 0.69314718f + __logf(v);
            float con = (l < 32) ? -den : 0.f;
#pragma unroll
            for (int off = 32; off > 0; off >>= 1) con += __shfl_xor(con, off);
            if (l == 0) atomicAdd(out, con);

        } else {
            // ================= staging waves (wid 1,2) =================
            const int par = wid - 1;
            auto stage_q = [&](int qq) {
                if (qq >= T/4) return;
                if (par == 0 && l < 32) {
#pragma unroll
                    for (int tt = 0; tt < 4; ++tt)
                        mls[qq & 3][tt][l] = mask[(4*qq + tt)*B + b0 + l];
                }
#pragma unroll
                for (int u = 0; u < 2; ++u) {
                    const int tt = 2*u + par;
                    const int t = 4*qq + tt;
                    const int slot = t & 15;
                    float4 ev[8];
#pragma unroll
                    for (int it = 0; it < 8; ++it) {
                        const int flat = it*64 + l;
                        ev[it] = *(const float4*)&emissions[((size_t)t*B + b0)*NT + flat*4];
                    }
#pragma unroll
                    for (int it = 0; it < 8; ++it) {
                        const int flat = it*64 + l;
                        const int n2 = flat >> 4;
                        const int j0 = (flat & 15) * 4;    // rows j0..j0+3
                        const int mt = j0 >> 5;
                        const int hg = (j0 >> 2) & 1;
                        const int g  = (j0 & 31) >> 3;
                        int2 wv;
                        wv.x = cvtpk(__expf(ev[it].x), __expf(ev[it].y));
                        wv.y = cvtpk(__expf(ev[it].z), __expf(ev[it].w));
                        *(int2*)&xw[slot][mt][hg][n2][2*g] = wv;
                    }
                }
            };
            stage_q(0); stage_q(1);
            __syncthreads();
#pragma unroll 1
            for (int q = 0; q < T/4; ++q) {
                stage_q(q + 2);
                __syncthreads();
            }
        }

    } else if (wid == 0) {
        // ================= numerator wave =================
        const int b = blockIdx.x - NWG;
        float acc = 0.f;
        int   cnt = 0;
#pragma unroll
        for (int m = 0; m < T / 64; ++m) {
            const int t  = l + 64 * m;
            const int mv = mask[t * B + b];
            const int tg = tags[t * B + b];
            cnt += (int)__popcll(__ballot(mv != 0));
            if (t == 0) {
                acc += startT[tg] + emissions[(size_t)b * NT + tg];
            } else if (mv) {
                const int tp = tags[(t - 1) * B + b];
                acc += trans[tp * NT + tg]
                     + emissions[(size_t)(t * B + b) * NT + tg];
            }
        }
#pragma unroll
        for (int off = 32; off > 0; off >>= 1)
            acc += __shfl_xor(acc, off);
        if (l == 0) {
            const int last = tags[(size_t)(cnt - 1) * B + b];
            atomicAdd(out, acc + endT[last]);
        }
    }
}

extern "C" void kernel_launch(void* const* d_in, const int* in_sizes, int n_in,
                              void* d_out, int out_size, void* d_ws, size_t ws_size,
                              hipStream_t stream) {
    const float* emissions = (const float*)d_in[0];
    const int*   tags      = (const int*)  d_in[1];
    const int*   mask      = (const int*)  d_in[2];
    const float* startT    = (const float*)d_in[3];
    const float* endT      = (const float*)d_in[4];
    const float* trans     = (const float*)d_in[5];
    float* out = (float*)d_out;

    hipMemsetAsync(out, 0, sizeof(float), stream);
    crf_mfma<<<NWG + B, 192, 0, stream>>>(
        emissions, tags, mask, startT, endT, trans, out);
}

// Round 6
// 247.479 us; speedup vs baseline: 1.1381x; 1.1381x over previous
//
#include <hip/hip_runtime.h>

#define T   512
#define B   512
#define NT  64
#define QS  16
#define NQ  (T / QS)
#define RING 4

typedef _Float16 h2 __attribute__((ext_vector_type(2)));
typedef _Float16 h8 __attribute__((ext_vector_type(8)));
typedef float    f4 __attribute__((ext_vector_type(4)));
typedef unsigned int uint;

__device__ __forceinline__ float rflf(float x) {
    return __uint_as_float(__builtin_amdgcn_readfirstlane(__float_as_uint(x)));
}
__device__ __forceinline__ int cvtpk(float a, float b) {
    return __builtin_bit_cast(int, __builtin_amdgcn_cvt_pkrtz(a, b));
}
__device__ __forceinline__ h2  bch2(int u) { return __builtin_bit_cast(h2, u); }
__device__ __forceinline__ int bci(h2 u)   { return __builtin_bit_cast(int, u); }

__device__ __forceinline__ float dot2(h2 a, h2 b, float c) {
#if __has_builtin(__builtin_amdgcn_fdot2)
    return __builtin_amdgcn_fdot2(a, b, c, false);
#else
    return c + (float)a.x * (float)b.x + (float)a.y * (float)b.y;
#endif
}

// ===========================================================================
// Kernel 1: full-GPU X = exp(emissions) pre-pack (f16 pairs, per-lane step
// order for the compute waves) + the numerator waves (4 batches / block).
// XP word (t, wv, h, l, w4): tags 32h + 8(l>>4) + 2*w4 + {0,1} of batch
// b = 16*wv + (l&15)  ->  one uint4 per thread, fully coalesced out.
// ===========================================================================
__global__ __launch_bounds__(256) void crf_prep(
    const float* __restrict__ emissions,  // [T, B, NT]
    const int*   __restrict__ tags,       // [T, B]
    const int*   __restrict__ mask,       // [T, B]
    const float* __restrict__ startT,
    const float* __restrict__ endT,
    const float* __restrict__ trans,
    uint4* __restrict__ xp,               // [T*32*2*64] uint4
    float* __restrict__ out)
{
    if (blockIdx.x < 8192) {
        const int lin = blockIdx.x * 256 + threadIdx.x;   // 0 .. 2,097,151
        const int l  = lin & 63;
        const int h  = (lin >> 6) & 1;
        const int wv = (lin >> 7) & 31;
        const int t  = lin >> 12;
        const int b  = wv * 16 + (l & 15);
        const int g  = l >> 4;
        const float* p = &emissions[((size_t)t * B + b) * NT + 32 * h + 8 * g];
        const float4 v0 = *(const float4*)p;
        const float4 v1 = *(const float4*)(p + 4);
        uint4 w;
        w.x = (uint)cvtpk(__expf(v0.x), __expf(v0.y));
        w.y = (uint)cvtpk(__expf(v0.z), __expf(v0.w));
        w.z = (uint)cvtpk(__expf(v1.x), __expf(v1.y));
        w.w = (uint)cvtpk(__expf(v1.z), __expf(v1.w));
        xp[lin] = w;
    } else {
        // ---- numerator: 4 waves / block, 1 batch / wave ----
        const int l  = threadIdx.x & 63;
        const int b  = (blockIdx.x - 8192) * 4 + (threadIdx.x >> 6);
        float acc = 0.f;
        int   cnt = 0;
#pragma unroll
        for (int m = 0; m < T / 64; ++m) {
            const int t  = l + 64 * m;
            const int mv = mask[t * B + b];
            const int tg = tags[t * B + b];
            cnt += (int)__popcll(__ballot(mv != 0));
            if (t == 0) {
                acc += startT[tg] + emissions[(size_t)b * NT + tg];
            } else if (mv) {
                const int tp = tags[(t - 1) * B + b];
                acc += trans[tp * NT + tg]
                     + emissions[(size_t)(t * B + b) * NT + tg];
            }
        }
#pragma unroll
        for (int off = 32; off > 0; off >>= 1)
            acc += __shfl_xor(acc, off);
        if (l == 0) {
            const int last = tags[(size_t)(cnt - 1) * B + b];
            atomicAdd(out, acc + endT[last]);
        }
    }
}

// ===========================================================================
// Kernel 2: 32 single-wave blocks, 16 batch-chains each, on the matrix pipe.
//
// State Q [64 tags x 16 cols] as B-fragments of mfma_f32_16x16x32_f16 under
// the pi-relabeling  tag(rho,g,u) = 32(rho>>1) + 8g + 4(rho&1) + u, chosen so
// C/D (verified m89: col=l&15, row=4*(l>>4)+reg) pairs convert to next-step B
// operands IN PLACE (zero cross-lane movement). State = 8 pair-words QW[w],
// w=2*rho+s, holding tags 32(w>>2)+8g+2(w&3)+{0,1} of column n=l&15 -- the
// SAME linear order as the XP words and the B elems (k-slot (g,e) -> tag
// 32c+8g+e for chunk c; A loads use the identical slot map, so the MFMA
// contraction is slot-consistent regardless of the HW k-permutation).
// Per step: 8 MFMA (4 indep 2-chains) + wave-uniform power-of-2 renorm
// (readfirstlane -> SGPR int-subtract) + 8 cvtpk + 8 pk_mul; exact
// per-column recenter every 4 steps via one ds_bpermute. X prefetched 4
// steps deep from the pre-packed buffer. No LDS, no barriers.
// ===========================================================================
__global__ __launch_bounds__(64) void crf_step(
    const float* __restrict__ emissions,
    const int*   __restrict__ mask,
    const float* __restrict__ startT,
    const float* __restrict__ endT,
    const float* __restrict__ trans,
    const uint4* __restrict__ xp,
    float* __restrict__ out)
{
    const int l  = threadIdx.x;
    const int wv = blockIdx.x;
    const int n  = l & 15;
    const int g  = l >> 4;
    const int b  = wv * 16 + n;

    // ---- constant A fragments: A[rho][c] elem e = E[k][j],
    //      k = 32c + 8g + e,  j = tag of output row m=l&15 of tile rho ----
    union AH { _Float16 e[8]; h8 v; };
    AH A[4][2];
#pragma unroll
    for (int rho = 0; rho < 4; ++rho)
#pragma unroll
        for (int c = 0; c < 2; ++c)
#pragma unroll
            for (int e = 0; e < 8; ++e) {
                const int k = 32 * c + 8 * g + e;
                const int j = 32 * (rho >> 1) + 4 * (rho & 1)
                            + 8 * (n >> 2) + (n & 3);
                A[rho][c].e[e] = (_Float16)__expf(trans[k * NT + j]);
            }

    // ---- init: q0 = exp(startT + em0 - S0) in QW order ----
    const float S0 = startT[0] + emissions[(size_t)b * NT];
    int QW[8];
    {
        const float* e0 = &emissions[(size_t)b * NT];
#pragma unroll
        for (int w = 0; w < 8; ++w) {
            const int tb = 32 * (w >> 2) + 8 * g + 2 * (w & 3);
            const float v0 = __expf(startT[tb]     + e0[tb]     - S0);
            const float v1 = __expf(startT[tb + 1] + e0[tb + 1] - S0);
            QW[w] = cvtpk(v0, v1);
        }
    }
    int K = 0;

    // ---- 4-deep prefetch (slot = t & 3) ----
    uint4 pfa[4], pfb[4];
    int   pfm[4];
    auto PF = [&](int t, int slot) {
        const int tc = t < T ? t : T - 1;
        const uint4* xb = xp + (size_t)(tc * 32 + wv) * 128 + l;
        pfa[slot] = xb[0];
        pfb[slot] = xb[64];
        pfm[slot] = mask[tc * B + b];
    };
    PF(1, 1); PF(2, 2); PF(3, 3); PF(4, 0);

    const f4 z4 = {0.f, 0.f, 0.f, 0.f};

#pragma unroll 1
    for (int base = 1; base < 512; base += 4) {
#pragma unroll
        for (int u = 0; u < 4; ++u) {
            const int t = base + u;
            if (t < 512) {
                const int slot = (1 + u) & 3;          // == t & 3
                const uint4 xlo = pfa[slot];
                const uint4 xhi = pfb[slot];
                const int   mv  = pfm[slot];
                PF(t + 4, slot);                       // refill after consume

                union HB { int w[4]; h8 v; };
                HB b0, b1;
                b0.w[0] = QW[0]; b0.w[1] = QW[1]; b0.w[2] = QW[2]; b0.w[3] = QW[3];
                b1.w[0] = QW[4]; b1.w[1] = QW[5]; b1.w[2] = QW[6]; b1.w[3] = QW[7];

                f4 c0 = __builtin_amdgcn_mfma_f32_16x16x32_f16(A[0][0].v, b0.v, z4, 0, 0, 0);
                f4 c1 = __builtin_amdgcn_mfma_f32_16x16x32_f16(A[1][0].v, b0.v, z4, 0, 0, 0);
                f4 c2 = __builtin_amdgcn_mfma_f32_16x16x32_f16(A[2][0].v, b0.v, z4, 0, 0, 0);
                f4 c3 = __builtin_amdgcn_mfma_f32_16x16x32_f16(A[3][0].v, b0.v, z4, 0, 0, 0);
                c0 = __builtin_amdgcn_mfma_f32_16x16x32_f16(A[0][1].v, b1.v, c0, 0, 0, 0);
                c1 = __builtin_amdgcn_mfma_f32_16x16x32_f16(A[1][1].v, b1.v, c1, 0, 0, 0);
                c2 = __builtin_amdgcn_mfma_f32_16x16x32_f16(A[2][1].v, b1.v, c2, 0, 0, 0);
                c3 = __builtin_amdgcn_mfma_f32_16x16x32_f16(A[3][1].v, b1.v, c3, 0, 0, 0);

                // wave-uniform power-of-2 renorm (target center 2^-2)
                const int bits = __builtin_amdgcn_readfirstlane(__float_as_int(c0[0]));
                const int kw   = ((bits >> 23) & 255) - 127;
                const int sb   = (kw + 2) << 23;

                auto cw = [&](float a, float bb2) {
                    return cvtpk(__int_as_float(__float_as_int(a)   - sb),
                                 __int_as_float(__float_as_int(bb2) - sb));
                };
                int nw[8];
                nw[0] = bci(bch2(cw(c0[0], c0[1])) * bch2((int)xlo.x));
                nw[1] = bci(bch2(cw(c0[2], c0[3])) * bch2((int)xlo.y));
                nw[2] = bci(bch2(cw(c1[0], c1[1])) * bch2((int)xlo.z));
                nw[3] = bci(bch2(cw(c1[2], c1[3])) * bch2((int)xlo.w));
                nw[4] = bci(bch2(cw(c2[0], c2[1])) * bch2((int)xhi.x));
                nw[5] = bci(bch2(cw(c2[2], c2[3])) * bch2((int)xhi.y));
                nw[6] = bci(bch2(cw(c3[0], c3[1])) * bch2((int)xhi.z));
                nw[7] = bci(bch2(cw(c3[2], c3[3])) * bch2((int)xhi.w));

                const bool mc = mv != 0;
                if (__ballot(mc) == ~0ull) {
#pragma unroll
                    for (int w = 0; w < 8; ++w) QW[w] = nw[w];
                    K += kw + 2;
                } else {
#pragma unroll
                    for (int w = 0; w < 8; ++w) QW[w] = mc ? nw[w] : QW[w];
                    K += mc ? (kw + 2) : 0;
                }

                if (u == 3) {
                    // exact per-column recenter (representation change only)
                    const int rep = __builtin_amdgcn_ds_bpermute(n << 2, QW[0]);
                    const int d   = ((rep >> 10) & 31) - 15;
                    int se = 13 - d;
                    se = se < 1 ? 1 : (se > 30 ? 30 : se);
                    const int sw = (se << 10) | (se << 26);
#pragma unroll
                    for (int w = 0; w < 8; ++w)
                        QW[w] = bci(bch2(QW[w]) * bch2(sw));
                    K += 15 - se;
                }
            }
        }
    }

    // ---- den_b = S0 + K*ln2 + log( sum_tags q * exp(endT) ) ----
    float v = 0.f;
#pragma unroll
    for (int w = 0; w < 8; ++w) {
        const int tb = 32 * (w >> 2) + 8 * g + 2 * (w & 3);
        const h2 qq = bch2(QW[w]);
        v += (float)qq.x * __expf(endT[tb]);
        v += (float)qq.y * __expf(endT[tb + 1]);
    }
    v += __shfl_xor(v, 16);
    v += __shfl_xor(v, 32);
    float con = 0.f;
    if (l < 16)
        con = -(S0 + (float)K * 0.69314718f + __logf(v));
#pragma unroll
    for (int off = 32; off > 0; off >>= 1)
        con += __shfl_xor(con, off);
    if (l == 0) atomicAdd(out, con);
}

// ===========================================================================
// Fallback (ws too small): round-3 kernel, verified ~110 us dispatch.
// ===========================================================================
__global__ __launch_bounds__(64) void crf_fused(
    const float* __restrict__ emissions,
    const int*   __restrict__ tags,
    const int*   __restrict__ mask,
    const float* __restrict__ startT,
    const float* __restrict__ endT,
    const float* __restrict__ trans,
    float* __restrict__ out)
{
    const int j = threadIdx.x;
    __shared__ __align__(16) float ebuf[RING][QS][NT];

    if (blockIdx.x < B) {
        const int b = blockIdx.x;
        h2 Eh[NT / 2];
#pragma unroll
        for (int m = 0; m < NT / 2; ++m) {
            Eh[m].x = (_Float16)__expf(trans[(2 * m)     * NT + j]);
            Eh[m].y = (_Float16)__expf(trans[(2 * m + 1) * NT + j]);
        }
        const int jr = j >> 4;
        const int c0 = (j & 15) * 4;
        float4 sA[4];
        auto issue_q = [&](int g) {
#pragma unroll
            for (int k = 0; k < 4; ++k) {
                const int t = g * QS + 4 * k + jr;
                sA[k] = *(const float4*)&emissions[((size_t)t * B + b) * NT + c0];
            }
        };
        auto write_q = [&](int g) {
#pragma unroll
            for (int k = 0; k < 4; ++k) {
                float4 w;
                w.x = __expf(sA[k].x); w.y = __expf(sA[k].y);
                w.z = __expf(sA[k].z); w.w = __expf(sA[k].w);
                *(float4*)&ebuf[g & (RING - 1)][4 * k + jr][c0] = w;
            }
        };
        for (int g = 0; g < 3; ++g) { issue_q(g); write_q(g); }
        issue_q(3);

        const float e0  = emissions[(size_t)b * NT + j];
        const float sc0 = startT[j] + e0;
        const float S0  = rflf(sc0);
        float q = __expf(sc0 - S0);
        int   K = 0;
        int pk_i;
        {
            const int qi = __float_as_int(q);
            const int qo = __builtin_amdgcn_update_dpp(0, qi, 0xB1, 0xF, 0xF, true);
            pk_i = cvtpk(q, __int_as_float(qo));
        }
        float* eflat = &ebuf[0][0][0];
        int bits_prev;
        int mpre = mask[j * B + b];
        unsigned long long mbc = 0;
        {
            int u[32];
#pragma unroll
            for (int m = 0; m < 32; ++m) u[m] = __builtin_amdgcn_readlane(pk_i, 2 * m);
            float a[8] = {0.f,0.f,0.f,0.f,0.f,0.f,0.f,0.f};
#pragma unroll
            for (int m = 0; m < 32; ++m) a[m & 7] = dot2(bch2(u[m]), Eh[m], a[m & 7]);
            const float p = ((a[0]+a[1])+(a[2]+a[3])) + ((a[4]+a[5])+(a[6]+a[7]));
            bits_prev = __builtin_amdgcn_readfirstlane(__float_as_int(p));
            const int  k = ((bits_prev >> 23) & 255) - 127;
            const float r = __int_as_float((125 - k) << 23);
            const float X1 = eflat[NT + j];
            const int  m1 = mask[B + b];
            if (m1) { q = (p * X1) * r; K = k + 2; }
            const int qo = __builtin_amdgcn_update_dpp(0, __float_as_int(q), 0xB1, 0xF, 0xF, true);
            pk_i = cvtpk(q, __int_as_float(qo));
        }
        float Xc = eflat[2 * NT + j];
        float Xn = eflat[3 * NT + j];
        auto stepF = [&](int s) {
            int u[32];
#pragma unroll
            for (int m = 0; m < 32; ++m) u[m] = __builtin_amdgcn_readlane(pk_i, 2 * m);
            __builtin_amdgcn_sched_barrier(0);
            const int  k = ((bits_prev >> 23) & 255) - 127;
            const float r = __int_as_float((125 - k) << 23);
            K += k + 2;
            float a[8] = {0.f,0.f,0.f,0.f,0.f,0.f,0.f,0.f};
#pragma unroll
            for (int m = 0; m < 32; ++m) a[m & 7] = dot2(bch2(u[m]), Eh[m], a[m & 7]);
            const float sXr = Xc * r;
            const float p = ((a[0]+a[1])+(a[2]+a[3])) + ((a[4]+a[5])+(a[6]+a[7]));
            q = p * sXr;
            bits_prev = __builtin_amdgcn_readfirstlane(__float_as_int(p));
            const int qo = __builtin_amdgcn_update_dpp(0, __float_as_int(q), 0xB1, 0xF, 0xF, true);
            pk_i = cvtpk(q, __int_as_float(qo));
            Xc = Xn;
            Xn = eflat[((s + 2) & 63) * NT + j];
        };
        auto stepM = [&](int s) {
            int u[32];
#pragma unroll
            for (int m = 0; m < 32; ++m) u[m] = __builtin_amdgcn_readlane(pk_i, 2 * m);
            __builtin_amdgcn_sched_barrier(0);
            const int  k = ((bits_prev >> 23) & 255) - 127;
            const float r = __int_as_float((125 - k) << 23);
            const bool mc = (mbc >> (s & 63)) & 1ull;
            const float mf = mc ? 1.0f : 0.0f;
            K += mc ? (k + 2) : 0;
            float a[8] = {0.f,0.f,0.f,0.f,0.f,0.f,0.f,0.f};
#pragma unroll
            for (int m = 0; m < 32; ++m) a[m & 7] = dot2(bch2(u[m]), Eh[m], a[m & 7]);
            const float sXr = Xc * r;
            const float p = ((a[0]+a[1])+(a[2]+a[3])) + ((a[4]+a[5])+(a[6]+a[7]));
            const float qn = p * sXr;
            q = fmaf(mf, qn - q, q);
            bits_prev = __builtin_amdgcn_readfirstlane(__float_as_int(p));
            const int qo = __builtin_amdgcn_update_dpp(0, __float_as_int(q), 0xB1, 0xF, 0xF, true);
            pk_i = cvtpk(q, __int_as_float(qo));
            Xc = Xn;
            Xn = eflat[((s + 2) & 63) * NT + j];
        };
        for (int x = 0; x < NQ; ++x) {
            const int gw = (x + 3 < NQ) ? x + 3 : NQ - 1;
            write_q(gw);
            const int gl = (x + 4 < NQ) ? x + 4 : NQ - 1;
            issue_q(gl);
            if ((x & 3) == 0) {
                mbc = __ballot(mpre != 0);
                const int cn = ((x >> 2) + 1 < 8) ? (x >> 2) + 1 : 7;
                mpre = mask[(cn * 64 + j) * B + b];
            }
            const unsigned qb = (unsigned)(mbc >> ((x & 3) << 4)) & 0xFFFFu;
            const int tt0 = (x == 0) ? 2 : 0;
            if (qb == 0xFFFFu) {
#pragma unroll 1
                for (int tt = tt0; tt < QS; ++tt) stepF(x * QS + tt);
            } else {
#pragma unroll 1
                for (int tt = tt0; tt < QS; ++tt) stepM(x * QS + tt);
            }
        }
        float v = q * __expf(endT[j]);
#pragma unroll
        for (int off = 32; off > 0; off >>= 1) v += __shfl_xor(v, off);
        if (j == 0)
            atomicAdd(out, -(S0 + (float)K * 0.69314718f + __logf(v)));
    } else {
        const int b = blockIdx.x - B;
        float acc = 0.f;
        int   cnt = 0;
#pragma unroll
        for (int m = 0; m < T / 64; ++m) {
            const int t  = j + 64 * m;
            const int mv = mask[t * B + b];
            const int tg = tags[t * B + b];
            cnt += (int)__popcll(__ballot(mv != 0));
            if (t == 0) {
                acc += startT[tg] + emissions[(size_t)b * NT + tg];
            } else if (mv) {
                const int tp = tags[(t - 1) * B + b];
                acc += trans[tp * NT + tg] + emissions[(size_t)(t * B + b) * NT + tg];
            }
        }
#pragma unroll
        for (int off = 32; off > 0; off >>= 1) acc += __shfl_xor(acc, off);
        if (j == 0) {
            const int last = tags[(size_t)(cnt - 1) * B + b];
            atomicAdd(out, acc + endT[last]);
        }
    }
}

extern "C" void kernel_launch(void* const* d_in, const int* in_sizes, int n_in,
                              void* d_out, int out_size, void* d_ws, size_t ws_size,
                              hipStream_t stream) {
    const float* emissions = (const float*)d_in[0];
    const int*   tags      = (const int*)  d_in[1];
    const int*   mask      = (const int*)  d_in[2];
    const float* startT    = (const float*)d_in[3];
    const float* endT      = (const float*)d_in[4];
    const float* trans     = (const float*)d_in[5];
    float* out = (float*)d_out;

    hipMemsetAsync(out, 0, sizeof(float), stream);

    const size_t need = (size_t)8192 * 256 * 16;   // 33.55 MB XP buffer
    if (d_ws != nullptr && ws_size >= need) {
        uint4* xp = (uint4*)d_ws;
        crf_prep<<<8192 + 128, 256, 0, stream>>>(emissions, tags, mask,
                                                 startT, endT, trans, xp, out);
        crf_step<<<32, 64, 0, stream>>>(emissions, mask, startT, endT, trans,
                                        xp, out);
    } else {
        crf_fused<<<2 * B, 64, 0, stream>>>(emissions, tags, mask, startT,
                                            endT, trans, out);
    }
}

// Round 7
// 156.849 us; speedup vs baseline: 1.7956x; 1.5778x over previous
//
#include <hip/hip_runtime.h>

#define T   512
#define B   512
#define NT  64
#define QS  16            // steps per staging quarter
#define NQ  (T / QS)      // 32 quarters total
#define FNQ 16            // fwd quarters 0..15  (steps 1..255)
#define RING 4            // LDS ring: 4 quarters = 64 rows, lead distance 3

typedef _Float16 h2 __attribute__((ext_vector_type(2)));

__device__ __forceinline__ float rflf(float x) {
    return __uint_as_float(__builtin_amdgcn_readfirstlane(__float_as_uint(x)));
}
__device__ __forceinline__ float dot2(h2 a, h2 b, float c) {
#if __has_builtin(__builtin_amdgcn_fdot2)
    return __builtin_amdgcn_fdot2(a, b, c, false);
#else
    return c + (float)a.x * (float)b.x + (float)a.y * (float)b.y;
#endif
}
__device__ __forceinline__ h2  bch2(int u) { return __builtin_bit_cast(h2, u); }
__device__ __forceinline__ int cvtpk(float a, float b) {
    return __builtin_bit_cast(int, __builtin_amdgcn_cvt_pkrtz(a, b));
}

// ---------------------------------------------------------------------------
// Round 7: five different step bodies all measured 520-585 cy/step -> the
// per-step chain latency is a wall; attack the DEPTH instead.
//   den = w^T (M511...M1) a0,  M_t = diag(X_t) E^T
//       = [ (M256^T ... M511^T) w ]^T . [ M255 ... M1 a0 ]
// Forward half (steps 1..255): round-3 verified body, quarters 0..15.
// Backward half (steps 511..256): v <- E (X_t (.) v)  -- E ROW pairs,
// descending staging over quarters 31..16, same lagged power-of-2 renorm.
// Both halves run concurrently (512+512 waves); a tiny combine kernel does
// den_b = S0 + (Kf+Kb) ln2 + log( sum_j qf_j * qb_j ).
// Numerator waves unchanged (blocks 1024..1535).
// ---------------------------------------------------------------------------
__global__ __launch_bounds__(64) void crf_main(
    const float* __restrict__ emissions,  // [T, B, NT]
    const int*   __restrict__ tags,       // [T, B]
    const int*   __restrict__ mask,       // [T, B]
    const float* __restrict__ startT,     // [NT]
    const float* __restrict__ endT,       // [NT]
    const float* __restrict__ trans,      // [NT, NT]
    float* __restrict__ wqf,              // [B][64]
    float* __restrict__ wqb,              // [B][64]
    float* __restrict__ wsf,              // [B]
    float* __restrict__ wsb,              // [B]
    float* __restrict__ out)
{
    const int j = threadIdx.x;
    __shared__ __align__(16) float ebuf[RING][QS][NT];

    if (blockIdx.x < B) {
        // =================== forward half, steps 1..255 =====================
        const int b = blockIdx.x;

        h2 Eh[NT / 2];                    // E column-j pairs over i
#pragma unroll
        for (int m = 0; m < NT / 2; ++m) {
            Eh[m].x = (_Float16)__expf(trans[(2 * m)     * NT + j]);
            Eh[m].y = (_Float16)__expf(trans[(2 * m + 1) * NT + j]);
        }

        const int jr = j >> 4;
        const int c0 = (j & 15) * 4;
        float4 sA[4];
        auto issue_q = [&](int g) {
#pragma unroll
            for (int k = 0; k < 4; ++k) {
                const int t = g * QS + 4 * k + jr;
                sA[k] = *(const float4*)&emissions[((size_t)t * B + b) * NT + c0];
            }
        };
        auto write_q = [&](int g) {
#pragma unroll
            for (int k = 0; k < 4; ++k) {
                float4 w;
                w.x = __expf(sA[k].x); w.y = __expf(sA[k].y);
                w.z = __expf(sA[k].z); w.w = __expf(sA[k].w);
                *(float4*)&ebuf[g & (RING - 1)][4 * k + jr][c0] = w;
            }
        };
        for (int g = 0; g < 3; ++g) { issue_q(g); write_q(g); }
        issue_q(3);

        const float e0  = emissions[(size_t)b * NT + j];
        const float sc0 = startT[j] + e0;
        const float S0  = rflf(sc0);
        float q = __expf(sc0 - S0);
        int   K = 0;
        int pk_i;
        {
            const int qi = __float_as_int(q);
            const int qo = __builtin_amdgcn_update_dpp(0, qi, 0xB1, 0xF, 0xF, true);
            pk_i = cvtpk(q, __int_as_float(qo));
        }
        float* eflat = &ebuf[0][0][0];
        int bits_prev;
        int mpre = mask[j * B + b];
        unsigned long long mbc = 0;

        {   // peeled step 1 (prompt renorm)
            int u[32];
#pragma unroll
            for (int m = 0; m < 32; ++m) u[m] = __builtin_amdgcn_readlane(pk_i, 2 * m);
            float a[8] = {0.f,0.f,0.f,0.f,0.f,0.f,0.f,0.f};
#pragma unroll
            for (int m = 0; m < 32; ++m) a[m & 7] = dot2(bch2(u[m]), Eh[m], a[m & 7]);
            const float p = ((a[0]+a[1])+(a[2]+a[3])) + ((a[4]+a[5])+(a[6]+a[7]));
            bits_prev = __builtin_amdgcn_readfirstlane(__float_as_int(p));
            const int  k = ((bits_prev >> 23) & 255) - 127;
            const float r = __int_as_float((125 - k) << 23);
            const float X1 = eflat[NT + j];
            const int  m1 = mask[B + b];
            if (m1) { q = (p * X1) * r; K = k + 2; }
            const int qo = __builtin_amdgcn_update_dpp(0, __float_as_int(q), 0xB1, 0xF, 0xF, true);
            pk_i = cvtpk(q, __int_as_float(qo));
        }
        float Xc = eflat[2 * NT + j];
        float Xn = eflat[3 * NT + j];

        auto stepF = [&](int s) {
            int u[32];
#pragma unroll
            for (int m = 0; m < 32; ++m) u[m] = __builtin_amdgcn_readlane(pk_i, 2 * m);
            __builtin_amdgcn_sched_barrier(0);
            const int  k = ((bits_prev >> 23) & 255) - 127;
            const float r = __int_as_float((125 - k) << 23);
            K += k + 2;
            float a[8] = {0.f,0.f,0.f,0.f,0.f,0.f,0.f,0.f};
#pragma unroll
            for (int m = 0; m < 32; ++m) a[m & 7] = dot2(bch2(u[m]), Eh[m], a[m & 7]);
            const float sXr = Xc * r;
            const float p = ((a[0]+a[1])+(a[2]+a[3])) + ((a[4]+a[5])+(a[6]+a[7]));
            q = p * sXr;
            bits_prev = __builtin_amdgcn_readfirstlane(__float_as_int(p));
            const int qo = __builtin_amdgcn_update_dpp(0, __float_as_int(q), 0xB1, 0xF, 0xF, true);
            pk_i = cvtpk(q, __int_as_float(qo));
            Xc = Xn;
            Xn = eflat[((s + 2) & 63) * NT + j];
        };
        auto stepM = [&](int s) {
            int u[32];
#pragma unroll
            for (int m = 0; m < 32; ++m) u[m] = __builtin_amdgcn_readlane(pk_i, 2 * m);
            __builtin_amdgcn_sched_barrier(0);
            const int  k = ((bits_prev >> 23) & 255) - 127;
            const float r = __int_as_float((125 - k) << 23);
            const bool mc = (mbc >> (s & 63)) & 1ull;
            const float mf = mc ? 1.0f : 0.0f;
            K += mc ? (k + 2) : 0;
            float a[8] = {0.f,0.f,0.f,0.f,0.f,0.f,0.f,0.f};
#pragma unroll
            for (int m = 0; m < 32; ++m) a[m & 7] = dot2(bch2(u[m]), Eh[m], a[m & 7]);
            const float sXr = Xc * r;
            const float p = ((a[0]+a[1])+(a[2]+a[3])) + ((a[4]+a[5])+(a[6]+a[7]));
            const float qn = p * sXr;
            q = fmaf(mf, qn - q, q);
            bits_prev = __builtin_amdgcn_readfirstlane(__float_as_int(p));
            const int qo = __builtin_amdgcn_update_dpp(0, __float_as_int(q), 0xB1, 0xF, 0xF, true);
            pk_i = cvtpk(q, __int_as_float(qo));
            Xc = Xn;
            Xn = eflat[((s + 2) & 63) * NT + j];
        };

        for (int x = 0; x < FNQ; ++x) {
            const int gw = (x + 3 < FNQ) ? x + 3 : FNQ - 1;
            write_q(gw);
            const int gl = (x + 4 < FNQ) ? x + 4 : FNQ - 1;
            issue_q(gl);
            if ((x & 3) == 0) {
                mbc = __ballot(mpre != 0);
                const int cn = ((x >> 2) + 1 < 4) ? (x >> 2) + 1 : 3;
                mpre = mask[(cn * 64 + j) * B + b];
            }
            const unsigned qb16 = (unsigned)(mbc >> ((x & 3) << 4)) & 0xFFFFu;
            const int tt0 = (x == 0) ? 2 : 0;
            if (qb16 == 0xFFFFu) {
#pragma unroll 1
                for (int tt = tt0; tt < QS; ++tt) stepF(x * QS + tt);
            } else {
#pragma unroll 1
                for (int tt = tt0; tt < QS; ++tt) stepM(x * QS + tt);
            }
        }
        wqf[b * 64 + j] = q;
        if (j == 0) wsf[b] = S0 + (float)K * 0.69314718f;

    } else if (blockIdx.x < 2 * B) {
        // ================== backward half, steps 511..256 ===================
        const int b = blockIdx.x - B;

        h2 Er[NT / 2];                    // E ROW-j pairs over i
#pragma unroll
        for (int m = 0; m < NT / 2; ++m) {
            Er[m].x = (_Float16)__expf(trans[j * NT + 2 * m]);
            Er[m].y = (_Float16)__expf(trans[j * NT + 2 * m + 1]);
        }

        const int jr = j >> 4;
        const int c0 = (j & 15) * 4;
        float4 sA[4];
        auto issue_q = [&](int g) {
#pragma unroll
            for (int k = 0; k < 4; ++k) {
                const int t = g * QS + 4 * k + jr;
                sA[k] = *(const float4*)&emissions[((size_t)t * B + b) * NT + c0];
            }
        };
        auto write_q = [&](int g) {
#pragma unroll
            for (int k = 0; k < 4; ++k) {
                float4 w;
                w.x = __expf(sA[k].x); w.y = __expf(sA[k].y);
                w.z = __expf(sA[k].z); w.w = __expf(sA[k].w);
                *(float4*)&ebuf[g & (RING - 1)][4 * k + jr][c0] = w;
            }
        };
        for (int g = 31; g > 28; --g) { issue_q(g); write_q(g); }
        issue_q(28);

        float v = __expf(endT[j]);
        int   K = 0;
        float* eflat = &ebuf[0][0][0];
        int bits_prev;
        int mpre = mask[(7 * 64 + j) * B + b];   // chunk-7 mask column
        unsigned long long mbc = 0;
        int pk_i;
        {   // pack y = v * X_511 for the peeled step
            const float y  = v * eflat[63 * NT + j];
            const int  yo = __builtin_amdgcn_update_dpp(0, __float_as_int(y), 0xB1, 0xF, 0xF, true);
            pk_i = cvtpk(y, __int_as_float(yo));
        }
        {   // peeled step 511 (prompt renorm)
            int u[32];
#pragma unroll
            for (int m = 0; m < 32; ++m) u[m] = __builtin_amdgcn_readlane(pk_i, 2 * m);
            float a[8] = {0.f,0.f,0.f,0.f,0.f,0.f,0.f,0.f};
#pragma unroll
            for (int m = 0; m < 32; ++m) a[m & 7] = dot2(bch2(u[m]), Er[m], a[m & 7]);
            const float p = ((a[0]+a[1])+(a[2]+a[3])) + ((a[4]+a[5])+(a[6]+a[7]));
            bits_prev = __builtin_amdgcn_readfirstlane(__float_as_int(p));
            const int  k = ((bits_prev >> 23) & 255) - 127;
            const float r = __int_as_float((125 - k) << 23);
            const int  m511 = mask[511 * B + b];
            if (m511) { v = p * r; K = k + 2; }
            const float y  = v * eflat[62 * NT + j];   // X_510
            const int  yo = __builtin_amdgcn_update_dpp(0, __float_as_int(y), 0xB1, 0xF, 0xF, true);
            pk_i = cvtpk(y, __int_as_float(yo));
        }

        // step s: consumes pk_i = pack(v * X_s); produces pack(v' * X_{s-1})
        auto bstepF = [&](int s) {
            int u[32];
#pragma unroll
            for (int m = 0; m < 32; ++m) u[m] = __builtin_amdgcn_readlane(pk_i, 2 * m);
            __builtin_amdgcn_sched_barrier(0);
            const int  k = ((bits_prev >> 23) & 255) - 127;
            const float r = __int_as_float((125 - k) << 23);
            K += k + 2;
            float a[8] = {0.f,0.f,0.f,0.f,0.f,0.f,0.f,0.f};
#pragma unroll
            for (int m = 0; m < 32; ++m) a[m & 7] = dot2(bch2(u[m]), Er[m], a[m & 7]);
            const float Xn = eflat[((s - 1) & 63) * NT + j];
            const float p = ((a[0]+a[1])+(a[2]+a[3])) + ((a[4]+a[5])+(a[6]+a[7]));
            v = p * r;
            bits_prev = __builtin_amdgcn_readfirstlane(__float_as_int(p));
            const float y  = v * Xn;
            const int  yo = __builtin_amdgcn_update_dpp(0, __float_as_int(y), 0xB1, 0xF, 0xF, true);
            pk_i = cvtpk(y, __int_as_float(yo));
        };
        auto bstepM = [&](int s) {
            int u[32];
#pragma unroll
            for (int m = 0; m < 32; ++m) u[m] = __builtin_amdgcn_readlane(pk_i, 2 * m);
            __builtin_amdgcn_sched_barrier(0);
            const int  k = ((bits_prev >> 23) & 255) - 127;
            const float r = __int_as_float((125 - k) << 23);
            const bool mc = (mbc >> (s & 63)) & 1ull;
            const float mf = mc ? 1.0f : 0.0f;
            K += mc ? (k + 2) : 0;
            float a[8] = {0.f,0.f,0.f,0.f,0.f,0.f,0.f,0.f};
#pragma unroll
            for (int m = 0; m < 32; ++m) a[m & 7] = dot2(bch2(u[m]), Er[m], a[m & 7]);
            const float Xn = eflat[((s - 1) & 63) * NT + j];
            const float p = ((a[0]+a[1])+(a[2]+a[3])) + ((a[4]+a[5])+(a[6]+a[7]));
            const float vn = p * r;
            v = fmaf(mf, vn - v, v);
            bits_prev = __builtin_amdgcn_readfirstlane(__float_as_int(p));
            const float y  = v * Xn;
            const int  yo = __builtin_amdgcn_update_dpp(0, __float_as_int(y), 0xB1, 0xF, 0xF, true);
            pk_i = cvtpk(y, __int_as_float(yo));
        };

        for (int x = NQ - 1; x >= 16; --x) {
            const int gw = (x - 3 >= 16) ? x - 3 : 16;
            write_q(gw);
            const int gl = (x - 4 >= 16) ? x - 4 : 16;
            issue_q(gl);
            if ((x & 3) == 3) {
                mbc = __ballot(mpre != 0);
                const int cn = ((x >> 2) - 1 > 4) ? (x >> 2) - 1 : 4;
                mpre = mask[(cn * 64 + j) * B + b];
            }
            const unsigned qb16 = (unsigned)(mbc >> ((x & 3) << 4)) & 0xFFFFu;
            const int tts = (x == NQ - 1) ? QS - 2 : QS - 1;
            if (qb16 == 0xFFFFu) {
#pragma unroll 1
                for (int tt = tts; tt >= 0; --tt) bstepF(x * QS + tt);
            } else {
#pragma unroll 1
                for (int tt = tts; tt >= 0; --tt) bstepM(x * QS + tt);
            }
        }
        wqb[b * 64 + j] = v;
        if (j == 0) wsb[b] = (float)K * 0.69314718f;

    } else {
        // ======================== numerator wave ============================
        const int b = blockIdx.x - 2 * B;
        float acc = 0.f;
        int   cnt = 0;
#pragma unroll
        for (int m = 0; m < T / 64; ++m) {
            const int t  = j + 64 * m;
            const int mv = mask[t * B + b];
            const int tg = tags[t * B + b];
            cnt += (int)__popcll(__ballot(mv != 0));
            if (t == 0) {
                acc += startT[tg] + emissions[(size_t)b * NT + tg];
            } else if (mv) {
                const int tp = tags[(t - 1) * B + b];
                acc += trans[tp * NT + tg]
                     + emissions[(size_t)(t * B + b) * NT + tg];
            }
        }
#pragma unroll
        for (int off = 32; off > 0; off >>= 1)
            acc += __shfl_xor(acc, off);
        if (j == 0) {
            const int last = tags[(size_t)(cnt - 1) * B + b];
            atomicAdd(out, acc + endT[last]);
        }
    }
}

// den_b = sf + sb + log( sum_j qf_j * qb_j )
__global__ __launch_bounds__(64) void crf_comb(
    const float* __restrict__ wqf, const float* __restrict__ wqb,
    const float* __restrict__ wsf, const float* __restrict__ wsb,
    float* __restrict__ out)
{
    const int b = blockIdx.x;
    const int j = threadIdx.x;
    float v = wqf[b * 64 + j] * wqb[b * 64 + j];
#pragma unroll
    for (int off = 32; off > 0; off >>= 1)
        v += __shfl_xor(v, off);
    if (j == 0)
        atomicAdd(out, -(wsf[b] + wsb[b] + __logf(v)));
}

// ===========================================================================
// Fallback (ws too small): round-3 kernel, verified ~110 us dispatch.
// ===========================================================================
__global__ __launch_bounds__(64) void crf_fused(
    const float* __restrict__ emissions,
    const int*   __restrict__ tags,
    const int*   __restrict__ mask,
    const float* __restrict__ startT,
    const float* __restrict__ endT,
    const float* __restrict__ trans,
    float* __restrict__ out)
{
    const int j = threadIdx.x;
    __shared__ __align__(16) float ebuf[RING][QS][NT];

    if (blockIdx.x < B) {
        const int b = blockIdx.x;
        h2 Eh[NT / 2];
#pragma unroll
        for (int m = 0; m < NT / 2; ++m) {
            Eh[m].x = (_Float16)__expf(trans[(2 * m)     * NT + j]);
            Eh[m].y = (_Float16)__expf(trans[(2 * m + 1) * NT + j]);
        }
        const int jr = j >> 4;
        const int c0 = (j & 15) * 4;
        float4 sA[4];
        auto issue_q = [&](int g) {
#pragma unroll
            for (int k = 0; k < 4; ++k) {
                const int t = g * QS + 4 * k + jr;
                sA[k] = *(const float4*)&emissions[((size_t)t * B + b) * NT + c0];
            }
        };
        auto write_q = [&](int g) {
#pragma unroll
            for (int k = 0; k < 4; ++k) {
                float4 w;
                w.x = __expf(sA[k].x); w.y = __expf(sA[k].y);
                w.z = __expf(sA[k].z); w.w = __expf(sA[k].w);
                *(float4*)&ebuf[g & (RING - 1)][4 * k + jr][c0] = w;
            }
        };
        for (int g = 0; g < 3; ++g) { issue_q(g); write_q(g); }
        issue_q(3);

        const float e0  = emissions[(size_t)b * NT + j];
        const float sc0 = startT[j] + e0;
        const float S0  = rflf(sc0);
        float q = __expf(sc0 - S0);
        int   K = 0;
        int pk_i;
        {
            const int qi = __float_as_int(q);
            const int qo = __builtin_amdgcn_update_dpp(0, qi, 0xB1, 0xF, 0xF, true);
            pk_i = cvtpk(q, __int_as_float(qo));
        }
        float* eflat = &ebuf[0][0][0];
        int bits_prev;
        int mpre = mask[j * B + b];
        unsigned long long mbc = 0;
        {
            int u[32];
#pragma unroll
            for (int m = 0; m < 32; ++m) u[m] = __builtin_amdgcn_readlane(pk_i, 2 * m);
            float a[8] = {0.f,0.f,0.f,0.f,0.f,0.f,0.f,0.f};
#pragma unroll
            for (int m = 0; m < 32; ++m) a[m & 7] = dot2(bch2(u[m]), Eh[m], a[m & 7]);
            const float p = ((a[0]+a[1])+(a[2]+a[3])) + ((a[4]+a[5])+(a[6]+a[7]));
            bits_prev = __builtin_amdgcn_readfirstlane(__float_as_int(p));
            const int  k = ((bits_prev >> 23) & 255) - 127;
            const float r = __int_as_float((125 - k) << 23);
            const float X1 = eflat[NT + j];
            const int  m1 = mask[B + b];
            if (m1) { q = (p * X1) * r; K = k + 2; }
            const int qo = __builtin_amdgcn_update_dpp(0, __float_as_int(q), 0xB1, 0xF, 0xF, true);
            pk_i = cvtpk(q, __int_as_float(qo));
        }
        float Xc = eflat[2 * NT + j];
        float Xn = eflat[3 * NT + j];
        auto stepF = [&](int s) {
            int u[32];
#pragma unroll
            for (int m = 0; m < 32; ++m) u[m] = __builtin_amdgcn_readlane(pk_i, 2 * m);
            __builtin_amdgcn_sched_barrier(0);
            const int  k = ((bits_prev >> 23) & 255) - 127;
            const float r = __int_as_float((125 - k) << 23);
            K += k + 2;
            float a[8] = {0.f,0.f,0.f,0.f,0.f,0.f,0.f,0.f};
#pragma unroll
            for (int m = 0; m < 32; ++m) a[m & 7] = dot2(bch2(u[m]), Eh[m], a[m & 7]);
            const float sXr = Xc * r;
            const float p = ((a[0]+a[1])+(a[2]+a[3])) + ((a[4]+a[5])+(a[6]+a[7]));
            q = p * sXr;
            bits_prev = __builtin_amdgcn_readfirstlane(__float_as_int(p));
            const int qo = __builtin_amdgcn_update_dpp(0, __float_as_int(q), 0xB1, 0xF, 0xF, true);
            pk_i = cvtpk(q, __int_as_float(qo));
            Xc = Xn;
            Xn = eflat[((s + 2) & 63) * NT + j];
        };
        auto stepM = [&](int s) {
            int u[32];
#pragma unroll
            for (int m = 0; m < 32; ++m) u[m] = __builtin_amdgcn_readlane(pk_i, 2 * m);
            __builtin_amdgcn_sched_barrier(0);
            const int  k = ((bits_prev >> 23) & 255) - 127;
            const float r = __int_as_float((125 - k) << 23);
            const bool mc = (mbc >> (s & 63)) & 1ull;
            const float mf = mc ? 1.0f : 0.0f;
            K += mc ? (k + 2) : 0;
            float a[8] = {0.f,0.f,0.f,0.f,0.f,0.f,0.f,0.f};
#pragma unroll
            for (int m = 0; m < 32; ++m) a[m & 7] = dot2(bch2(u[m]), Eh[m], a[m & 7]);
            const float sXr = Xc * r;
            const float p = ((a[0]+a[1])+(a[2]+a[3])) + ((a[4]+a[5])+(a[6]+a[7]));
            const float qn = p * sXr;
            q = fmaf(mf, qn - q, q);
            bits_prev = __builtin_amdgcn_readfirstlane(__float_as_int(p));
            const int qo = __builtin_amdgcn_update_dpp(0, __float_as_int(q), 0xB1, 0xF, 0xF, true);
            pk_i = cvtpk(q, __int_as_float(qo));
            Xc = Xn;
            Xn = eflat[((s + 2) & 63) * NT + j];
        };
        for (int x = 0; x < NQ; ++x) {
            const int gw = (x + 3 < NQ) ? x + 3 : NQ - 1;
            write_q(gw);
            const int gl = (x + 4 < NQ) ? x + 4 : NQ - 1;
            issue_q(gl);
            if ((x & 3) == 0) {
                mbc = __ballot(mpre != 0);
                const int cn = ((x >> 2) + 1 < 8) ? (x >> 2) + 1 : 7;
                mpre = mask[(cn * 64 + j) * B + b];
            }
            const unsigned qb16 = (unsigned)(mbc >> ((x & 3) << 4)) & 0xFFFFu;
            const int tt0 = (x == 0) ? 2 : 0;
            if (qb16 == 0xFFFFu) {
#pragma unroll 1
                for (int tt = tt0; tt < QS; ++tt) stepF(x * QS + tt);
            } else {
#pragma unroll 1
                for (int tt = tt0; tt < QS; ++tt) stepM(x * QS + tt);
            }
        }
        float v = q * __expf(endT[j]);
#pragma unroll
        for (int off = 32; off > 0; off >>= 1) v += __shfl_xor(v, off);
        if (j == 0)
            atomicAdd(out, -(S0 + (float)K * 0.69314718f + __logf(v)));
    } else {
        const int b = blockIdx.x - B;
        float acc = 0.f;
        int   cnt = 0;
#pragma unroll
        for (int m = 0; m < T / 64; ++m) {
            const int t  = j + 64 * m;
            const int mv = mask[t * B + b];
            const int tg = tags[t * B + b];
            cnt += (int)__popcll(__ballot(mv != 0));
            if (t == 0) {
                acc += startT[tg] + emissions[(size_t)b * NT + tg];
            } else if (mv) {
                const int tp = tags[(t - 1) * B + b];
                acc += trans[tp * NT + tg] + emissions[(size_t)(t * B + b) * NT + tg];
            }
        }
#pragma unroll
        for (int off = 32; off > 0; off >>= 1) acc += __shfl_xor(acc, off);
        if (j == 0) {
            const int last = tags[(size_t)(cnt - 1) * B + b];
            atomicAdd(out, acc + endT[last]);
        }
    }
}

extern "C" void kernel_launch(void* const* d_in, const int* in_sizes, int n_in,
                              void* d_out, int out_size, void* d_ws, size_t ws_size,
                              hipStream_t stream) {
    const float* emissions = (const float*)d_in[0];
    const int*   tags      = (const int*)  d_in[1];
    const int*   mask      = (const int*)  d_in[2];
    const float* startT    = (const float*)d_in[3];
    const float* endT      = (const float*)d_in[4];
    const float* trans     = (const float*)d_in[5];
    float* out = (float*)d_out;

    hipMemsetAsync(out, 0, sizeof(float), stream);

    const size_t need = (size_t)(B * 64 * 2 + 2 * B) * sizeof(float); // ~262 KB
    if (d_ws != nullptr && ws_size >= need) {
        float* wqf = (float*)d_ws;
        float* wqb = wqf + B * 64;
        float* wsf = wqb + B * 64;
        float* wsb = wsf + B;
        crf_main<<<3 * B, 64, 0, stream>>>(emissions, tags, mask, startT, endT,
                                           trans, wqf, wqb, wsf, wsb, out);
        crf_comb<<<B, 64, 0, stream>>>(wqf, wqb, wsf, wsb, out);
    } else {
        crf_fused<<<2 * B, 64, 0, stream>>>(emissions, tags, mask, startT,
                                            endT, trans, out);
    }
}